// Round 7
// baseline (196.626 us; speedup 1.0000x reference)
//
#include <hip/hip_runtime.h>

// Sinkhorn loss, single-pass moment formulation.
//   s_t = relu(v_t); X_t = cumsum(s); Sx = sum_t X_t
//   loss_p = sum_t t * (X_t/Sx - Y_t/Sy)^2 ;  out = sum_p loss_p
// Chunk j (local cumsums L,M; exclusive offsets O,P; g = isx*O - isy*P):
//   sum_{t in j} t*(isx*X - isy*Y)^2 = g^2*T_j + 2g*(isx*pL - isy*pM)
//        + isx^2*pLL - 2*isx*isy*pLM + isy^2*pMM
// Two ws-size-adaptive paths (branch on ws_size is constant per process ->
// graph-safe; suspected round-5/6 container crashes were d_ws overrun at
// 36 MiB footprint):
//   Path A (ws >= 38 MiB): CH=256/LCH=16, p1 blocks stream CONTIGUOUS 256 KB.
//   Path B (fallback):     CH=64/LCH=64 strided column-walk (round-4 proven).

#define NT 4096
#define NP 4096

// ======================= Path A: CH=256, contiguous =======================
#define A_CH  256
#define A_LCH 16
#define A_B1  1024
#define A_B2  512

__global__ __launch_bounds__(A_B1, 4) void p1_moments_a(
    const float* __restrict__ x, const float* __restrict__ y,
    float* __restrict__ aX, float* __restrict__ aY,
    float* __restrict__ uL, float* __restrict__ uM,
    float* __restrict__ pL, float* __restrict__ pM,
    float* __restrict__ pLL, float* __restrict__ pMM,
    float* __restrict__ pLM)
{
  const int tid = threadIdx.x;        // 0..1023, 4 columns each (float4)
  const int j   = blockIdx.x;         // chunk
  const int t0  = j * A_LCH;
  const float4* xb = (const float4*)x + (size_t)t0 * (NP / 4) + tid;
  const float4* yb = (const float4*)y + (size_t)t0 * (NP / 4) + tid;

  float cx[4] = {0,0,0,0}, cy[4] = {0,0,0,0};
  float auL[4] = {0,0,0,0}, auM[4] = {0,0,0,0};
  float apL[4] = {0,0,0,0}, apM[4] = {0,0,0,0};
  float aLL[4] = {0,0,0,0}, aMM[4] = {0,0,0,0}, aLM[4] = {0,0,0,0};

#pragma unroll 4
  for (int i = 0; i < A_LCH; ++i) {
    const float4 xv = xb[(size_t)i * (NP / 4)];
    const float4 yv = yb[(size_t)i * (NP / 4)];
    const float t = (float)(t0 + i);
    const float lx[4] = {xv.x, xv.y, xv.z, xv.w};
    const float ly[4] = {yv.x, yv.y, yv.z, yv.w};
#pragma unroll
    for (int k = 0; k < 4; ++k) {
      const float sx = fmaxf(lx[k], 0.f);
      const float sy = fmaxf(ly[k], 0.f);
      cx[k] += sx;  cy[k] += sy;
      const float tl = t * cx[k], tm = t * cy[k];
      apL[k] += tl;                  apM[k] += tm;
      aLL[k] = fmaf(tl, cx[k], aLL[k]);
      aMM[k] = fmaf(tm, cy[k], aMM[k]);
      aLM[k] = fmaf(tl, cy[k], aLM[k]);
      auL[k] += cx[k];               auM[k] += cy[k];
    }
  }

  const size_t o = (size_t)j * NP;
  ((float4*)(aX  + o))[tid] = make_float4(cx[0],  cx[1],  cx[2],  cx[3]);
  ((float4*)(aY  + o))[tid] = make_float4(cy[0],  cy[1],  cy[2],  cy[3]);
  ((float4*)(uL  + o))[tid] = make_float4(auL[0], auL[1], auL[2], auL[3]);
  ((float4*)(uM  + o))[tid] = make_float4(auM[0], auM[1], auM[2], auM[3]);
  ((float4*)(pL  + o))[tid] = make_float4(apL[0], apL[1], apL[2], apL[3]);
  ((float4*)(pM  + o))[tid] = make_float4(apM[0], apM[1], apM[2], apM[3]);
  ((float4*)(pLL + o))[tid] = make_float4(aLL[0], aLL[1], aLL[2], aLL[3]);
  ((float4*)(pMM + o))[tid] = make_float4(aMM[0], aMM[1], aMM[2], aMM[3]);
  ((float4*)(pLM + o))[tid] = make_float4(aLM[0], aLM[1], aLM[2], aLM[3]);
}

// block = 512 threads = 64 columns (lane) x 8 chunk-groups (g); each thread
// serially walks 32 chunks, loads coalesced across lanes.
__global__ __launch_bounds__(A_B2) void p2_loss_a(
    const float* __restrict__ aX, const float* __restrict__ aY,
    const float* __restrict__ uL, const float* __restrict__ uM,
    const float* __restrict__ pL, const float* __restrict__ pM,
    const float* __restrict__ pLL, const float* __restrict__ pMM,
    const float* __restrict__ pLM,
    double* __restrict__ part)
{
  const int lane = threadIdx.x & 63;
  const int g    = threadIdx.x >> 6;        // 0..7
  const int p    = blockIdx.x * 64 + lane;
  const int j0   = g * 32;

  double ox = 0, oy = 0, s1x = 0, s1y = 0;
#pragma unroll 4
  for (int jj = 0; jj < 32; ++jj) {
    const size_t off = (size_t)(j0 + jj) * NP + p;
    s1x += (double)A_LCH * ox + (double)uL[off];
    s1y += (double)A_LCH * oy + (double)uM[off];
    ox += (double)aX[off];  oy += (double)aY[off];
  }

  __shared__ double Axs[8][64], Ays[8][64], Pxs[8][64], Pys[8][64];
  Axs[g][lane] = ox;  Ays[g][lane] = oy;
  Pxs[g][lane] = s1x; Pys[g][lane] = s1y;
  __syncthreads();

  double Qx = 0, Qy = 0, Sx = 0, Sy = 0, Qx_own = 0, Qy_own = 0;
#pragma unroll
  for (int gg = 0; gg < 8; ++gg) {
    if (gg == g) { Qx_own = Qx; Qy_own = Qy; }
    Sx += 512.0 * Qx + Pxs[gg][lane];   // 512 = A_LCH * 32 chunks/group
    Sy += 512.0 * Qy + Pys[gg][lane];
    Qx += Axs[gg][lane];
    Qy += Ays[gg][lane];
  }
  const double isx = 1.0 / Sx, isy = 1.0 / Sy;

  double O = Qx_own, P = Qy_own, loss = 0;
#pragma unroll 4
  for (int jj = 0; jj < 32; ++jj) {
    const int jr = j0 + jj;
    const size_t off = (size_t)jr * NP + p;
    const double gg = isx * O - isy * P;
    const double Tj = 256.0 * (double)jr + 120.0;
    const double sh  = isx * (double)pL[off] - isy * (double)pM[off];
    const double shh = isx * isx * (double)pLL[off]
                     - 2.0 * isx * isy * (double)pLM[off]
                     + isy * isy * (double)pMM[off];
    loss += gg * gg * Tj + 2.0 * gg * sh + shh;
    O += (double)aX[off];  P += (double)aY[off];
  }

  for (int m = 32; m; m >>= 1) loss += __shfl_xor(loss, m, 64);
  __shared__ double wred[8];
  if (lane == 0) wred[g] = loss;
  __syncthreads();
  if (threadIdx.x == 0) {
    double v = 0;
#pragma unroll
    for (int i = 0; i < 8; ++i) v += wred[i];
    part[blockIdx.x] = v;
  }
}

__global__ __launch_bounds__(64) void p3_final_a(
    const double* __restrict__ part, float* __restrict__ out)
{
  double v = part[threadIdx.x];   // exactly 64 partials
  for (int m = 32; m; m >>= 1) v += __shfl_xor(v, m, 64);
  if (threadIdx.x == 0) out[0] = (float)v;
}

// ================= Path B: CH=64 column-walk (round-4 proven) =================
#define B_CH  64
#define B_LCH 64
#define B_BLK 256

__global__ __launch_bounds__(B_BLK) void p1_moments_b(
    const float* __restrict__ x, const float* __restrict__ y,
    float* __restrict__ aX, float* __restrict__ aY,
    float* __restrict__ uL, float* __restrict__ uM,
    float* __restrict__ pL, float* __restrict__ pM,
    float* __restrict__ pLL, float* __restrict__ pMM,
    float* __restrict__ pLM)
{
  const int pv = blockIdx.x * B_BLK + threadIdx.x;  // float2 col
  const int j  = blockIdx.y;
  const int t0 = j * B_LCH;
  const float2* xb = (const float2*)x + (size_t)t0 * (NP / 2) + pv;
  const float2* yb = (const float2*)y + (size_t)t0 * (NP / 2) + pv;

  float cx0 = 0.f, cx1 = 0.f, cy0 = 0.f, cy1 = 0.f;
  float uL0 = 0.f, uL1 = 0.f, uM0 = 0.f, uM1 = 0.f;
  float pL0 = 0.f, pL1 = 0.f, pM0 = 0.f, pM1 = 0.f;
  float pLL0 = 0.f, pLL1 = 0.f, pMM0 = 0.f, pMM1 = 0.f;
  float pLM0 = 0.f, pLM1 = 0.f;

#pragma unroll 8
  for (int i = 0; i < B_LCH; ++i) {
    const float2 xv = xb[(size_t)i * (NP / 2)];
    const float2 yv = yb[(size_t)i * (NP / 2)];
    const float t = (float)(t0 + i);

    const float lx0 = fmaxf(xv.x, 0.f), lx1 = fmaxf(xv.y, 0.f);
    const float ly0 = fmaxf(yv.x, 0.f), ly1 = fmaxf(yv.y, 0.f);

    cx0 += lx0; cy0 += ly0;
    const float tl0 = t * cx0, tm0 = t * cy0;
    pL0  += tl0;                  pM0  += tm0;
    pLL0 = fmaf(tl0, cx0, pLL0);  pMM0 = fmaf(tm0, cy0, pMM0);
    pLM0 = fmaf(tl0, cy0, pLM0);
    uL0  += cx0;                  uM0  += cy0;

    cx1 += lx1; cy1 += ly1;
    const float tl1 = t * cx1, tm1 = t * cy1;
    pL1  += tl1;                  pM1  += tm1;
    pLL1 = fmaf(tl1, cx1, pLL1);  pMM1 = fmaf(tm1, cy1, pMM1);
    pLM1 = fmaf(tl1, cy1, pLM1);
    uL1  += cx1;                  uM1  += cy1;
  }

  const size_t o2 = (size_t)j * (NP / 2) + pv;
  ((float2*)aX)[o2]  = make_float2(cx0, cx1);
  ((float2*)aY)[o2]  = make_float2(cy0, cy1);
  ((float2*)uL)[o2]  = make_float2(uL0, uL1);
  ((float2*)uM)[o2]  = make_float2(uM0, uM1);
  ((float2*)pL)[o2]  = make_float2(pL0, pL1);
  ((float2*)pM)[o2]  = make_float2(pM0, pM1);
  ((float2*)pLL)[o2] = make_float2(pLL0, pLL1);
  ((float2*)pMM)[o2] = make_float2(pMM0, pMM1);
  ((float2*)pLM)[o2] = make_float2(pLM0, pLM1);
}

__global__ __launch_bounds__(B_BLK) void p2_loss_b(
    const float* __restrict__ aX, const float* __restrict__ aY,
    const float* __restrict__ uL, const float* __restrict__ uM,
    const float* __restrict__ pL, const float* __restrict__ pM,
    const float* __restrict__ pLL, const float* __restrict__ pMM,
    const float* __restrict__ pLM,
    double* __restrict__ part)
{
  const int wave = threadIdx.x >> 6;           // 4 waves per block
  const int lane = threadIdx.x & 63;           // = chunk j
  const int p    = blockIdx.x * 4 + wave;
  const size_t o = (size_t)lane * NP + p;

  const double a  = (double)aX[o];
  const double b  = (double)aY[o];
  const double ul = (double)uL[o];
  const double um = (double)uM[o];

  double sx = a, sy = b;
  for (int d = 1; d < 64; d <<= 1) {
    const double tx = __shfl_up(sx, d, 64);
    const double ty = __shfl_up(sy, d, 64);
    if (lane >= d) { sx += tx; sy += ty; }
  }
  const double O = sx - a;
  const double P = sy - b;

  double vx = (double)B_LCH * O + ul;
  double vy = (double)B_LCH * P + um;
  for (int m = 32; m; m >>= 1) {
    vx += __shfl_xor(vx, m, 64);
    vy += __shfl_xor(vy, m, 64);
  }
  const double isx = 1.0 / vx;
  const double isy = 1.0 / vy;

  const double g   = isx * O - isy * P;
  const double Tj  = 4096.0 * (double)lane + 2016.0;
  const double sh  = isx * (double)pL[o] - isy * (double)pM[o];
  const double shh = isx * isx * (double)pLL[o]
                   - 2.0 * isx * isy * (double)pLM[o]
                   + isy * isy * (double)pMM[o];
  double loss = g * g * Tj + 2.0 * g * sh + shh;

  for (int m = 32; m; m >>= 1) loss += __shfl_xor(loss, m, 64);
  if (lane == 0) part[p] = loss;
}

__global__ __launch_bounds__(1024) void p3_final_b(
    const double* __restrict__ part, float* __restrict__ out)
{
  __shared__ double red[1024];
  double v = 0.0;
  for (int i = threadIdx.x; i < NP; i += 1024) v += part[i];
  red[threadIdx.x] = v;
  __syncthreads();
  for (int s = 512; s > 0; s >>= 1) {
    if (threadIdx.x < s) red[threadIdx.x] += red[threadIdx.x + s];
    __syncthreads();
  }
  if (threadIdx.x == 0) out[0] = (float)red[0];
}

// =============================== launcher ===============================
extern "C" void kernel_launch(void* const* d_in, const int* in_sizes, int n_in,
                              void* d_out, int out_size, void* d_ws, size_t ws_size,
                              hipStream_t stream) {
  const float* x = (const float*)d_in[0];
  const float* y = (const float*)d_in[1];
  float* out = (float*)d_out;

  const size_t cnpA = (size_t)A_CH * NP;                    // 1M elems
  const size_t needA = 9 * cnpA * sizeof(float)
                     + (size_t)(NP / 64) * sizeof(double) + 256;

  if (ws_size >= needA) {
    char* ws = (char*)d_ws;
    float* aX  = (float*)ws; ws += cnpA * sizeof(float);
    float* aY  = (float*)ws; ws += cnpA * sizeof(float);
    float* uLp = (float*)ws; ws += cnpA * sizeof(float);
    float* uMp = (float*)ws; ws += cnpA * sizeof(float);
    float* pLp = (float*)ws; ws += cnpA * sizeof(float);
    float* pMp = (float*)ws; ws += cnpA * sizeof(float);
    float* pLLp = (float*)ws; ws += cnpA * sizeof(float);
    float* pMMp = (float*)ws; ws += cnpA * sizeof(float);
    float* pLMp = (float*)ws; ws += cnpA * sizeof(float);
    double* part = (double*)ws;

    p1_moments_a<<<A_CH, A_B1, 0, stream>>>(x, y, aX, aY, uLp, uMp, pLp, pMp, pLLp, pMMp, pLMp);
    p2_loss_a<<<NP / 64, A_B2, 0, stream>>>(aX, aY, uLp, uMp, pLp, pMp, pLLp, pMMp, pLMp, part);
    p3_final_a<<<1, 64, 0, stream>>>(part, out);
  } else {
    const size_t cnpB = (size_t)B_CH * NP;                  // 256K elems
    char* ws = (char*)d_ws;
    float* aX  = (float*)ws; ws += cnpB * sizeof(float);
    float* aY  = (float*)ws; ws += cnpB * sizeof(float);
    float* uLp = (float*)ws; ws += cnpB * sizeof(float);
    float* uMp = (float*)ws; ws += cnpB * sizeof(float);
    float* pLp = (float*)ws; ws += cnpB * sizeof(float);
    float* pMp = (float*)ws; ws += cnpB * sizeof(float);
    float* pLLp = (float*)ws; ws += cnpB * sizeof(float);
    float* pMMp = (float*)ws; ws += cnpB * sizeof(float);
    float* pLMp = (float*)ws; ws += cnpB * sizeof(float);
    double* part = (double*)ws;

    dim3 g1((NP / 2) / B_BLK, B_CH);
    p1_moments_b<<<g1, B_BLK, 0, stream>>>(x, y, aX, aY, uLp, uMp, pLp, pMp, pLLp, pMMp, pLMp);
    p2_loss_b<<<NP / 4, B_BLK, 0, stream>>>(aX, aY, uLp, uMp, pLp, pMp, pLLp, pMMp, pLMp, part);
    p3_final_b<<<1, 1024, 0, stream>>>(part, out);
  }
}

// Round 9
// 190.191 us; speedup vs baseline: 1.0338x; 1.0338x over previous
//
#include <hip/hip_runtime.h>

// Sinkhorn loss, single-pass moment formulation.
//   s_t = relu(v_t); X_t = cumsum(s); Sx = sum_t X_t
//   loss_p = sum_t t * (X_t/Sx - Y_t/Sy)^2 ;  out = sum_p loss_p
// Chunk j (LCH=32 rows; local cumsums L,M; exclusive offsets O,P):
//   sum_{t in j} t*(isx*X - isy*Y)^2 = g^2*T_j + 2g*(isx*pL - isy*pM)
//        + isx^2*pLL - 2*isx*isy*pLM + isy^2*pMM,  g = isx*O - isy*P,
//   T_j = 1024*j + 496,  Sx = sum_j (32*O_j + uL_j).
// R8: p1 at 32 waves/CU (2048 blocks, VGPR<=64) with 8-deep load batching --
// MLP/occupancy is the suspected limiter (R1/R4/R7: BW tracks waves, not
// access pattern). p2 = R4-proven wave-per-column gather (2 chunks/lane).

#define NT   4096
#define NP   4096
#define CH   128    // chunks
#define LCH  32     // rows per chunk; CH*LCH == NT
#define BLK  256

__global__ __launch_bounds__(BLK, 8) void p1_moments(
    const float* __restrict__ x, const float* __restrict__ y,
    float* __restrict__ aX, float* __restrict__ aY,
    float* __restrict__ uL, float* __restrict__ uM,
    float* __restrict__ pL, float* __restrict__ pM,
    float* __restrict__ pLL, float* __restrict__ pMM,
    float* __restrict__ pLM)
{
  const int p  = blockIdx.x * BLK + threadIdx.x;  // column, scalar
  const int j  = blockIdx.y;                      // chunk
  const int t0 = j * LCH;
  const float* xp = x + (size_t)t0 * NP + p;
  const float* yp = y + (size_t)t0 * NP + p;

  float c_x = 0.f, c_y = 0.f;
  float uLa = 0.f, uMa = 0.f, pLa = 0.f, pMa = 0.f;
  float LLa = 0.f, MMa = 0.f, LMa = 0.f;

  for (int g = 0; g < LCH / 8; ++g) {             // 4 groups, kept rolled
    float xs[8], ys[8];
#pragma unroll
    for (int i = 0; i < 8; ++i) {                 // 16 loads batched up front
      xs[i] = xp[(size_t)(g * 8 + i) * NP];
      ys[i] = yp[(size_t)(g * 8 + i) * NP];
    }
#pragma unroll
    for (int i = 0; i < 8; ++i) {
      const float t = (float)(t0 + g * 8 + i);
      c_x += fmaxf(xs[i], 0.f);
      c_y += fmaxf(ys[i], 0.f);
      const float tl = t * c_x, tm = t * c_y;
      pLa += tl;                  pMa += tm;
      LLa = fmaf(tl, c_x, LLa);   MMa = fmaf(tm, c_y, MMa);
      LMa = fmaf(tl, c_y, LMa);
      uLa += c_x;                 uMa += c_y;
    }
  }

  const size_t o = (size_t)j * NP + p;            // coalesced stores
  aX[o]  = c_x;  aY[o]  = c_y;
  uL[o]  = uLa;  uM[o]  = uMa;
  pL[o]  = pLa;  pM[o]  = pMa;
  pLL[o] = LLa;  pMM[o] = MMa;  pLM[o] = LMa;
}

// One wave per column p; lane handles chunks j0=2*lane, j0+1.
__global__ __launch_bounds__(BLK) void p2_loss(
    const float* __restrict__ aX, const float* __restrict__ aY,
    const float* __restrict__ uL, const float* __restrict__ uM,
    const float* __restrict__ pL, const float* __restrict__ pM,
    const float* __restrict__ pLL, const float* __restrict__ pMM,
    const float* __restrict__ pLM,
    double* __restrict__ part)
{
  const int wave = threadIdx.x >> 6;              // 4 waves per block
  const int lane = threadIdx.x & 63;
  const int p    = blockIdx.x * 4 + wave;
  const int j0   = 2 * lane;
  const size_t o0 = (size_t)j0 * NP + p;
  const size_t o1 = o0 + NP;

  const double a0 = (double)aX[o0], a1 = (double)aX[o1];
  const double b0 = (double)aY[o0], b1 = (double)aY[o1];
  const double ul0 = (double)uL[o0], ul1 = (double)uL[o1];
  const double um0 = (double)uM[o0], um1 = (double)uM[o1];

  // inclusive shuffle scan of per-lane sums -> exclusive lane offsets
  const double sA = a0 + a1, sB = b0 + b1;
  double ix = sA, iy = sB;
  for (int d = 1; d < 64; d <<= 1) {
    const double tx = __shfl_up(ix, d, 64);
    const double ty = __shfl_up(iy, d, 64);
    if (lane >= d) { ix += tx; iy += ty; }
  }
  const double O0 = ix - sA;        // offset before chunk j0
  const double P0 = iy - sB;
  const double O1 = O0 + a0;        // offset before chunk j0+1
  const double P1 = P0 + b0;

  // Sx = sum_j (32*O_j + uL_j), butterfly (all lanes get total)
  double vx = (double)LCH * (O0 + O1) + ul0 + ul1;
  double vy = (double)LCH * (P0 + P1) + um0 + um1;
  for (int m = 32; m; m >>= 1) {
    vx += __shfl_xor(vx, m, 64);
    vy += __shfl_xor(vy, m, 64);
  }
  const double isx = 1.0 / vx;
  const double isy = 1.0 / vy;

  // loss for the lane's two chunks
  double loss = 0.0;
  {
    const double g   = isx * O0 - isy * P0;
    const double Tj  = 1024.0 * (double)j0 + 496.0;
    const double sh  = isx * (double)pL[o0] - isy * (double)pM[o0];
    const double shh = isx * isx * (double)pLL[o0]
                     - 2.0 * isx * isy * (double)pLM[o0]
                     + isy * isy * (double)pMM[o0];
    loss += g * g * Tj + 2.0 * g * sh + shh;
  }
  {
    const double g   = isx * O1 - isy * P1;
    const double Tj  = 1024.0 * (double)(j0 + 1) + 496.0;
    const double sh  = isx * (double)pL[o1] - isy * (double)pM[o1];
    const double shh = isx * isx * (double)pLL[o1]
                     - 2.0 * isx * isy * (double)pLM[o1]
                     + isy * isy * (double)pMM[o1];
    loss += g * g * Tj + 2.0 * g * sh + shh;
  }

  for (int m = 32; m; m >>= 1) loss += __shfl_xor(loss, m, 64);
  if (lane == 0) part[p] = loss;
}

__global__ __launch_bounds__(1024) void p3_final(
    const double* __restrict__ part, float* __restrict__ out)
{
  __shared__ double red[1024];
  double v = 0.0;
  for (int i = threadIdx.x; i < NP; i += 1024) v += part[i];
  red[threadIdx.x] = v;
  __syncthreads();
  for (int s = 512; s > 0; s >>= 1) {
    if (threadIdx.x < s) red[threadIdx.x] += red[threadIdx.x + s];
    __syncthreads();
  }
  if (threadIdx.x == 0) out[0] = (float)red[0];
}

extern "C" void kernel_launch(void* const* d_in, const int* in_sizes, int n_in,
                              void* d_out, int out_size, void* d_ws, size_t ws_size,
                              hipStream_t stream) {
  const float* x = (const float*)d_in[0];
  const float* y = (const float*)d_in[1];
  float* out = (float*)d_out;

  const size_t CNP = (size_t)CH * NP;             // 512K elems per array
  char* ws = (char*)d_ws;
  float* aX  = (float*)ws; ws += CNP * sizeof(float);
  float* aY  = (float*)ws; ws += CNP * sizeof(float);
  float* uLp = (float*)ws; ws += CNP * sizeof(float);
  float* uMp = (float*)ws; ws += CNP * sizeof(float);
  float* pLp = (float*)ws; ws += CNP * sizeof(float);
  float* pMp = (float*)ws; ws += CNP * sizeof(float);
  float* pLLp = (float*)ws; ws += CNP * sizeof(float);
  float* pMMp = (float*)ws; ws += CNP * sizeof(float);
  float* pLMp = (float*)ws; ws += CNP * sizeof(float);
  double* part = (double*)ws; ws += (size_t)NP * sizeof(double);

  dim3 g1(NP / BLK, CH);                          // 16 x 128 = 2048 blocks
  p1_moments<<<g1, BLK, 0, stream>>>(x, y, aX, aY, uLp, uMp, pLp, pMp, pLLp, pMMp, pLMp);
  p2_loss<<<NP / 4, BLK, 0, stream>>>(aX, aY, uLp, uMp, pLp, pMp, pLLp, pMMp, pLMp, part);
  p3_final<<<1, 1024, 0, stream>>>(part, out);
}